// Round 1
// baseline (888.530 us; speedup 1.0000x reference)
//
#include <hip/hip_runtime.h>
#include <hip/hip_bf16.h>
#include <cstdint>

#define NN 50000
#define NE 1600000
#define DV 256
#define DA 128

using floatx4 = __attribute__((ext_vector_type(4))) float;
using shortx8 = __attribute__((ext_vector_type(8))) short;

__device__ __forceinline__ unsigned short f2bf(float f) {
    union { float f; uint32_t u; } v; v.f = f;
    uint32_t u = v.u;
    uint32_t r = (u + 0x7FFFu + ((u >> 16) & 1u)) >> 16;   // RNE
    return (unsigned short)r;
}
__device__ __forceinline__ float bflo(uint32_t u) {
    union { uint32_t u; float f; } v; v.u = u << 16; return v.f;
}
__device__ __forceinline__ float bfhi(uint32_t u) {
    union { uint32_t u; float f; } v; v.u = u & 0xFFFF0000u; return v.f;
}

// ---------------- cast weights fp32 -> bf16 (tiny, once per launch) -------
__global__ void cast_w_kernel(const float* __restrict__ wq, const float* __restrict__ wk,
                              const float* __restrict__ wv, unsigned short* __restrict__ out) {
    int i = blockIdx.x * blockDim.x + threadIdx.x;
    if (i < 32768)       out[i] = f2bf(wq[i]);
    else if (i < 65536)  out[i] = f2bf(wk[i - 32768]);
    else if (i < 81920)  out[i] = f2bf(wv[i - 65536]);
}

// ---------------- Q/K projection: O = lrelu(A[M,K] * W[128,K]^T + b) -> bf16
template<int K>
__global__ __launch_bounds__(256)
void proj_gemm(const float* __restrict__ A, const unsigned short* __restrict__ Wbf,
               const float* __restrict__ bias, unsigned short* __restrict__ Obf, int M) {
    __shared__ unsigned short Al[64 * 32];
    __shared__ unsigned short Bl[128 * 32];
    const int tid = threadIdx.x;
    const int lane = tid & 63, w = tid >> 6;
    const int m0 = blockIdx.x * 64;

    floatx4 acc[8];
#pragma unroll
    for (int i = 0; i < 8; ++i) acc[i] = (floatx4)0.0f;

    for (int kk = 0; kk < K; kk += 32) {
        // stage A tile 64x32 fp32->bf16 (2 float4 per thread)
#pragma unroll
        for (int it = 0; it < 2; ++it) {
            int j = tid + it * 256;            // 0..511
            int row = j >> 3;
            int c4 = (j & 7) * 4;
            float4 f = make_float4(0.f, 0.f, 0.f, 0.f);
            int gm = m0 + row;
            if (gm < M) f = *reinterpret_cast<const float4*>(A + (size_t)gm * K + kk + c4);
            ushort4 u; u.x = f2bf(f.x); u.y = f2bf(f.y); u.z = f2bf(f.z); u.w = f2bf(f.w);
            *reinterpret_cast<ushort4*>(&Al[row * 32 + c4]) = u;
        }
        // stage B tile 128x32 bf16 (one uint4 = 8 bf16 per thread, x2)
#pragma unroll
        for (int it = 0; it < 2; ++it) {
            int j = tid + it * 256;            // 0..511
            int row = j >> 2;
            int c8 = (j & 3) * 8;
            uint4 v = *reinterpret_cast<const uint4*>(Wbf + (size_t)row * K + kk + c8);
            *reinterpret_cast<uint4*>(&Bl[row * 32 + c8]) = v;
        }
        __syncthreads();
        shortx8 af = *reinterpret_cast<const shortx8*>(&Al[(w * 16 + (lane & 15)) * 32 + 8 * (lane >> 4)]);
#pragma unroll
        for (int nt = 0; nt < 8; ++nt) {
            shortx8 bf = *reinterpret_cast<const shortx8*>(&Bl[(nt * 16 + (lane & 15)) * 32 + 8 * (lane >> 4)]);
            acc[nt] = __builtin_amdgcn_mfma_f32_16x16x32_bf16(af, bf, acc[nt], 0, 0, 0);
        }
        __syncthreads();
    }
    // epilogue: bias + lrelu -> bf16.  D: row = 4*(lane>>4)+reg, col = lane&15
    const int col = lane & 15;
    const int rbase = m0 + w * 16 + 4 * (lane >> 4);
#pragma unroll
    for (int nt = 0; nt < 8; ++nt) {
        int gn = nt * 16 + col;
        float b = bias[gn];
#pragma unroll
        for (int reg = 0; reg < 4; ++reg) {
            int gm = rbase + reg;
            if (gm < M) {
                float v = acc[nt][reg] + b;
                v = v > 0.f ? v : 0.01f * v;
                Obf[(size_t)gm * 128 + gn] = f2bf(v);
            }
        }
    }
}

// ---------------- per-edge logits: p = exp(q[r].k[s]/sqrt(128)), denom += p
__global__ void logits_kernel(const unsigned short* __restrict__ qbf,
                              const unsigned short* __restrict__ kbf,
                              const int* __restrict__ sidx, const int* __restrict__ ridx,
                              float* __restrict__ p, float* __restrict__ denom) {
    int e = blockIdx.x * blockDim.x + threadIdx.x;
    if (e >= NE) return;
    int s = sidx[e], r = ridx[e];
    const uint4* qp = reinterpret_cast<const uint4*>(qbf + (size_t)r * 128);
    const uint4* kp = reinterpret_cast<const uint4*>(kbf + (size_t)s * 128);
    float acc = 0.f;
#pragma unroll
    for (int i = 0; i < 16; ++i) {
        uint4 qa = qp[i], ka = kp[i];
        acc += bflo(qa.x) * bflo(ka.x) + bfhi(qa.x) * bfhi(ka.x);
        acc += bflo(qa.y) * bflo(ka.y) + bfhi(qa.y) * bfhi(ka.y);
        acc += bflo(qa.z) * bflo(ka.z) + bfhi(qa.z) * bfhi(ka.z);
        acc += bflo(qa.w) * bflo(ka.w) + bfhi(qa.w) * bfhi(ka.w);
    }
    float pe = __expf(acc * 0.08838834764831845f);   // 1/sqrt(128); logits bounded ~[0,3]
    p[e] = pe;
    atomicAdd(&denom[r], pe);
}

// ---------------- V projection + scatter: out[r[e],:] += p[e]*lrelu(edges[e]*Wv^T+bv)
__global__ __launch_bounds__(256)
void v_gemm_scatter(const float* __restrict__ Ed, const unsigned short* __restrict__ Wv,
                    const float* __restrict__ bv, const float* __restrict__ p,
                    const int* __restrict__ ridx, float* __restrict__ out) {
    constexpr int K = 128;
    __shared__ unsigned short Al[64 * 32];
    __shared__ unsigned short Bl[128 * 32];
    const int tid = threadIdx.x;
    const int lane = tid & 63, w = tid >> 6;
    const int m0 = blockIdx.x * 64;   // NE % 64 == 0, no tail

    floatx4 acc[8];
#pragma unroll
    for (int i = 0; i < 8; ++i) acc[i] = (floatx4)0.0f;

    for (int kk = 0; kk < K; kk += 32) {
#pragma unroll
        for (int it = 0; it < 2; ++it) {
            int j = tid + it * 256;
            int row = j >> 3;
            int c4 = (j & 7) * 4;
            float4 f = *reinterpret_cast<const float4*>(Ed + (size_t)(m0 + row) * K + kk + c4);
            ushort4 u; u.x = f2bf(f.x); u.y = f2bf(f.y); u.z = f2bf(f.z); u.w = f2bf(f.w);
            *reinterpret_cast<ushort4*>(&Al[row * 32 + c4]) = u;
        }
#pragma unroll
        for (int it = 0; it < 2; ++it) {
            int j = tid + it * 256;
            int row = j >> 2;
            int c8 = (j & 3) * 8;
            uint4 v = *reinterpret_cast<const uint4*>(Wv + (size_t)row * K + kk + c8);
            *reinterpret_cast<uint4*>(&Bl[row * 32 + c8]) = v;
        }
        __syncthreads();
        shortx8 af = *reinterpret_cast<const shortx8*>(&Al[(w * 16 + (lane & 15)) * 32 + 8 * (lane >> 4)]);
#pragma unroll
        for (int nt = 0; nt < 8; ++nt) {
            shortx8 bf = *reinterpret_cast<const shortx8*>(&Bl[(nt * 16 + (lane & 15)) * 32 + 8 * (lane >> 4)]);
            acc[nt] = __builtin_amdgcn_mfma_f32_16x16x32_bf16(af, bf, acc[nt], 0, 0, 0);
        }
        __syncthreads();
    }
    const int col = lane & 15;
    const int ebase = m0 + w * 16 + 4 * (lane >> 4);
    float pe[4]; int re[4];
#pragma unroll
    for (int reg = 0; reg < 4; ++reg) { pe[reg] = p[ebase + reg]; re[reg] = ridx[ebase + reg]; }
#pragma unroll
    for (int nt = 0; nt < 8; ++nt) {
        int gn = nt * 16 + col;
        float b = bv[gn];
#pragma unroll
        for (int reg = 0; reg < 4; ++reg) {
            float v = acc[nt][reg] + b;
            v = v > 0.f ? v : 0.01f * v;
            atomicAdd(&out[(size_t)re[reg] * 128 + gn], v * pe[reg]);
        }
    }
}

// ---------------- normalize: out /= denom[node] (0 if empty segment) ------
__global__ void normalize_kernel(float* __restrict__ out, const float* __restrict__ denom) {
    int i = blockIdx.x * blockDim.x + threadIdx.x;   // one float4 each
    if (i >= NN * 128 / 4) return;
    int node = (i * 4) >> 7;
    float d = denom[node];
    float inv = d > 0.f ? 1.0f / d : 0.f;
    float4* o = reinterpret_cast<float4*>(out) + i;
    float4 v = *o;
    v.x *= inv; v.y *= inv; v.z *= inv; v.w *= inv;
    *o = v;
}

extern "C" void kernel_launch(void* const* d_in, const int* in_sizes, int n_in,
                              void* d_out, int out_size, void* d_ws, size_t ws_size,
                              hipStream_t stream) {
    const float* nodes = (const float*)d_in[0];
    const float* edges = (const float*)d_in[1];
    const int*   eidx  = (const int*)d_in[2];     // [2, NE]: row0 = sender, row1 = receiver
    const float* Wq = (const float*)d_in[3];
    const float* bq = (const float*)d_in[4];
    const float* Wk = (const float*)d_in[5];
    const float* bk = (const float*)d_in[6];
    const float* Wv = (const float*)d_in[7];
    const float* bv = (const float*)d_in[8];
    const int* sidx = eidx;
    const int* ridx = eidx + NE;

    // workspace layout (all 16B-aligned):
    // [0,163840)               Wq_bf | Wk_bf | Wv_bf   (81920 ushorts)
    // [163840, +12.8MB)        q_bf [NN,128]
    // [.., +12.8MB)            k_bf [NN,128]
    // [.., +6.4MB)             p [NE] fp32
    // [.., +200KB)             denom [NN] fp32           total ~32.4 MB
    char* ws = (char*)d_ws;
    unsigned short* wq_bf = (unsigned short*)ws;
    unsigned short* wk_bf = wq_bf + 32768;
    unsigned short* wv_bf = wq_bf + 65536;
    unsigned short* q_bf = (unsigned short*)(ws + 163840);
    unsigned short* k_bf = q_bf + (size_t)NN * 128;
    float* p     = (float*)(ws + 163840 + 2 * (size_t)NN * 128 * 2);
    float* denom = p + NE;
    float* out = (float*)d_out;

    hipMemsetAsync(out, 0, (size_t)NN * 128 * 4, stream);
    hipMemsetAsync(denom, 0, (size_t)NN * 4, stream);

    cast_w_kernel<<<320, 256, 0, stream>>>(Wq, Wk, Wv, wq_bf);
    proj_gemm<256><<<(NN + 63) / 64, 256, 0, stream>>>(nodes, wq_bf, bq, q_bf, NN);
    proj_gemm<256><<<(NN + 63) / 64, 256, 0, stream>>>(nodes, wk_bf, bk, k_bf, NN);
    logits_kernel<<<(NE + 255) / 256, 256, 0, stream>>>(q_bf, k_bf, sidx, ridx, p, denom);
    v_gemm_scatter<<<NE / 64, 256, 0, stream>>>(edges, wv_bf, bv, p, ridx, out);
    normalize_kernel<<<(NN * 128 / 4 + 255) / 256, 256, 0, stream>>>(out, denom);
}

// Round 2
// 876.266 us; speedup vs baseline: 1.0140x; 1.0140x over previous
//
#include <hip/hip_runtime.h>
#include <hip/hip_bf16.h>
#include <cstdint>

#define NN 50000
#define NE 1600000
#define DV 256
#define DA 128

using floatx4 = __attribute__((ext_vector_type(4))) float;
using shortx8 = __attribute__((ext_vector_type(8))) short;

__device__ __forceinline__ unsigned short f2bf(float f) {
    union { float f; uint32_t u; } v; v.f = f;
    uint32_t u = v.u;
    uint32_t r = (u + 0x7FFFu + ((u >> 16) & 1u)) >> 16;   // RNE
    return (unsigned short)r;
}
__device__ __forceinline__ float bflo(uint32_t u) {
    union { uint32_t u; float f; } v; v.u = u << 16; return v.f;
}
__device__ __forceinline__ float bfhi(uint32_t u) {
    union { uint32_t u; float f; } v; v.u = u & 0xFFFF0000u; return v.f;
}

// ---------------- cast weights fp32 -> bf16 -------------------------------
__global__ void cast_w_kernel(const float* __restrict__ wq, const float* __restrict__ wk,
                              const float* __restrict__ wv, unsigned short* __restrict__ out) {
    int i = blockIdx.x * blockDim.x + threadIdx.x;
    if (i < 32768)       out[i] = f2bf(wq[i]);
    else if (i < 65536)  out[i] = f2bf(wk[i - 32768]);
    else if (i < 81920)  out[i] = f2bf(wv[i - 65536]);
}

// ---------------- sort-by-receiver infrastructure -------------------------
__global__ void hist_kernel(const int* __restrict__ ridx, int* __restrict__ cnt) {
    int e = blockIdx.x * blockDim.x + threadIdx.x;
    if (e < NE) atomicAdd(&cnt[ridx[e]], 1);
}

// single-block exclusive scan of cnt[NN] -> offs[NN]
__global__ __launch_bounds__(1024)
void scan_kernel(const int* __restrict__ cnt, int* __restrict__ offs) {
    __shared__ int part[1024];
    const int tid = threadIdx.x;
    const int PER = (NN + 1023) / 1024;   // 49
    int base = tid * PER;
    int s = 0;
    for (int i = 0; i < PER; ++i) { int idx = base + i; if (idx < NN) s += cnt[idx]; }
    part[tid] = s;
    __syncthreads();
    for (int off = 1; off < 1024; off <<= 1) {
        int v = (tid >= off) ? part[tid - off] : 0;
        __syncthreads();
        part[tid] += v;
        __syncthreads();
    }
    int excl = (tid == 0) ? 0 : part[tid - 1];
    for (int i = 0; i < PER; ++i) {
        int idx = base + i;
        if (idx < NN) { offs[idx] = excl; excl += cnt[idx]; }
    }
}

// scatter edges into receiver-sorted order; offs used as running cursor
__global__ void scatter_kernel(const int* __restrict__ ridx, int* __restrict__ offs,
                               int* __restrict__ perm, int* __restrict__ rs) {
    int e = blockIdx.x * blockDim.x + threadIdx.x;
    if (e >= NE) return;
    int r = ridx[e];
    int pos = atomicAdd(&offs[r], 1);
    perm[pos] = e;
    rs[pos] = r;
}

// ---------------- fused Q,K projection: [NN,256] x [256,256]^T ------------
// W stacked: rows 0..127 = Wq, 128..255 = Wk (contiguous in ws)
__global__ __launch_bounds__(256)
void proj_qk(const float* __restrict__ A, const unsigned short* __restrict__ Wst,
             const float* __restrict__ bq, const float* __restrict__ bk,
             unsigned short* __restrict__ qbf, unsigned short* __restrict__ kbf, int M) {
    __shared__ unsigned short Al[64 * 32];
    __shared__ unsigned short Bl[256 * 32];
    const int tid = threadIdx.x;
    const int lane = tid & 63, w = tid >> 6;
    const int m0 = blockIdx.x * 64;
    constexpr int K = 256;

    floatx4 acc[16];
#pragma unroll
    for (int i = 0; i < 16; ++i) acc[i] = (floatx4)0.0f;

    for (int kk = 0; kk < K; kk += 32) {
#pragma unroll
        for (int it = 0; it < 2; ++it) {
            int j = tid + it * 256;
            int row = j >> 3;
            int c4 = (j & 7) * 4;
            float4 f = make_float4(0.f, 0.f, 0.f, 0.f);
            int gm = m0 + row;
            if (gm < M) f = *reinterpret_cast<const float4*>(A + (size_t)gm * K + kk + c4);
            ushort4 u; u.x = f2bf(f.x); u.y = f2bf(f.y); u.z = f2bf(f.z); u.w = f2bf(f.w);
            *reinterpret_cast<ushort4*>(&Al[row * 32 + c4]) = u;
        }
#pragma unroll
        for (int it = 0; it < 4; ++it) {
            int j = tid + it * 256;          // 0..1023
            int row = j >> 2;                // 0..255
            int c8 = (j & 3) * 8;
            uint4 v = *reinterpret_cast<const uint4*>(Wst + (size_t)row * K + kk + c8);
            *reinterpret_cast<uint4*>(&Bl[row * 32 + c8]) = v;
        }
        __syncthreads();
        shortx8 af = *reinterpret_cast<const shortx8*>(&Al[(w * 16 + (lane & 15)) * 32 + 8 * (lane >> 4)]);
#pragma unroll
        for (int nt = 0; nt < 16; ++nt) {
            shortx8 bf = *reinterpret_cast<const shortx8*>(&Bl[(nt * 16 + (lane & 15)) * 32 + 8 * (lane >> 4)]);
            acc[nt] = __builtin_amdgcn_mfma_f32_16x16x32_bf16(af, bf, acc[nt], 0, 0, 0);
        }
        __syncthreads();
    }
    const int col = lane & 15;
    const int rbase = m0 + w * 16 + 4 * (lane >> 4);
#pragma unroll
    for (int nt = 0; nt < 16; ++nt) {
        int gn = nt * 16 + col;
        bool isq = gn < 128;
        int oc = isq ? gn : gn - 128;
        float b = isq ? bq[oc] : bk[oc];
        unsigned short* O = isq ? qbf : kbf;
#pragma unroll
        for (int reg = 0; reg < 4; ++reg) {
            int gm = rbase + reg;
            if (gm < M) {
                float v = acc[nt][reg] + b;
                v = v > 0.f ? v : 0.01f * v;
                O[(size_t)gm * 128 + oc] = f2bf(v);
            }
        }
    }
}

// ---------------- per-edge logits in sorted order -------------------------
__global__ void logits_kernel(const unsigned short* __restrict__ qbf,
                              const unsigned short* __restrict__ kbf,
                              const int* __restrict__ sidx,
                              const int* __restrict__ perm, const int* __restrict__ rs,
                              float* __restrict__ p, float* __restrict__ denom) {
    int pos = blockIdx.x * blockDim.x + threadIdx.x;
    if (pos >= NE) return;
    int e = perm[pos];
    int r = rs[pos], s = sidx[e];
    const uint4* qp = reinterpret_cast<const uint4*>(qbf + (size_t)r * 128);
    const uint4* kp = reinterpret_cast<const uint4*>(kbf + (size_t)s * 128);
    float acc = 0.f;
#pragma unroll
    for (int i = 0; i < 16; ++i) {
        uint4 qa = qp[i], ka = kp[i];
        acc += bflo(qa.x) * bflo(ka.x) + bfhi(qa.x) * bfhi(ka.x);
        acc += bflo(qa.y) * bflo(ka.y) + bfhi(qa.y) * bfhi(ka.y);
        acc += bflo(qa.z) * bflo(ka.z) + bfhi(qa.z) * bfhi(ka.z);
        acc += bflo(qa.w) * bflo(ka.w) + bfhi(qa.w) * bfhi(ka.w);
    }
    float pe = __expf(acc * 0.08838834764831845f);
    p[pos] = pe;
    atomicAdd(&denom[r], pe);
}

// ---------------- normalize p in place ------------------------------------
__global__ void pnorm_kernel(float* __restrict__ p, const int* __restrict__ rs,
                             const float* __restrict__ denom) {
    int pos = blockIdx.x * blockDim.x + threadIdx.x;
    if (pos >= NE) return;
    p[pos] = p[pos] / denom[rs[pos]];
}

// ---------------- V projection + in-block segment reduction ---------------
__global__ __launch_bounds__(256)
void v_gemm_seg(const float* __restrict__ Ed, const unsigned short* __restrict__ Wv,
                const float* __restrict__ bv, const float* __restrict__ p,
                const int* __restrict__ perm, const int* __restrict__ rs,
                float* __restrict__ out) {
    constexpr int K = 128;
    constexpr int VLD = 129;                    // padded row stride (floats)
    __shared__ float Vl[64 * VLD];              // 33 KB; staging aliased inside
    __shared__ int segstart[64];
    __shared__ int segnode[64];
    __shared__ int nseg_s;
    unsigned short* Al = reinterpret_cast<unsigned short*>(Vl);          // 4 KB
    unsigned short* Bl = reinterpret_cast<unsigned short*>(Vl) + 2048;   // 8 KB

    const int tid = threadIdx.x;
    const int lane = tid & 63, w = tid >> 6;
    const int m0 = blockIdx.x * 64;             // NE % 64 == 0

    // segment boundaries within this block's 64 sorted edges (wave 0)
    if (w == 0) {
        int r = rs[m0 + lane];
        int prev = (lane == 0) ? -1 : rs[m0 + lane - 1];
        bool flag = (lane == 0) || (r != prev);
        unsigned long long mask = __ballot(flag);
        int ns = __popcll(mask);
        int pos = __popcll(mask & ((1ull << lane) - 1ull));
        if (flag) { segstart[pos] = lane; segnode[pos] = r; }
        if (lane == 0) nseg_s = ns;
    }

    // gathered edge ids for A staging (2 rows per thread)
    const int row0 = tid >> 3;                  // 0..31
    const int e0 = perm[m0 + row0];
    const int e1 = perm[m0 + row0 + 32];
    const int c4 = (tid & 7) * 4;

    floatx4 acc[8];
#pragma unroll
    for (int i = 0; i < 8; ++i) acc[i] = (floatx4)0.0f;

    for (int kk = 0; kk < K; kk += 32) {
        {
            float4 f0 = *reinterpret_cast<const float4*>(Ed + (size_t)e0 * K + kk + c4);
            float4 f1 = *reinterpret_cast<const float4*>(Ed + (size_t)e1 * K + kk + c4);
            ushort4 u0; u0.x = f2bf(f0.x); u0.y = f2bf(f0.y); u0.z = f2bf(f0.z); u0.w = f2bf(f0.w);
            ushort4 u1; u1.x = f2bf(f1.x); u1.y = f2bf(f1.y); u1.z = f2bf(f1.z); u1.w = f2bf(f1.w);
            *reinterpret_cast<ushort4*>(&Al[row0 * 32 + c4]) = u0;
            *reinterpret_cast<ushort4*>(&Al[(row0 + 32) * 32 + c4]) = u1;
        }
#pragma unroll
        for (int it = 0; it < 2; ++it) {
            int j = tid + it * 256;
            int row = j >> 2;
            int c8 = (j & 3) * 8;
            uint4 v = *reinterpret_cast<const uint4*>(Wv + (size_t)row * K + kk + c8);
            *reinterpret_cast<uint4*>(&Bl[row * 32 + c8]) = v;
        }
        __syncthreads();
        shortx8 af = *reinterpret_cast<const shortx8*>(&Al[(w * 16 + (lane & 15)) * 32 + 8 * (lane >> 4)]);
#pragma unroll
        for (int nt = 0; nt < 8; ++nt) {
            shortx8 bf = *reinterpret_cast<const shortx8*>(&Bl[(nt * 16 + (lane & 15)) * 32 + 8 * (lane >> 4)]);
            acc[nt] = __builtin_amdgcn_mfma_f32_16x16x32_bf16(af, bf, acc[nt], 0, 0, 0);
        }
        __syncthreads();
    }

    // epilogue: bias + lrelu, scale by p, stash in LDS (Vl overwrites staging)
    const int col = lane & 15;
    const int lrbase = w * 16 + 4 * (lane >> 4);
    float pe[4];
#pragma unroll
    for (int reg = 0; reg < 4; ++reg) pe[reg] = p[m0 + lrbase + reg];
#pragma unroll
    for (int nt = 0; nt < 8; ++nt) {
        int gn = nt * 16 + col;
        float b = bv[gn];
#pragma unroll
        for (int reg = 0; reg < 4; ++reg) {
            float v = acc[nt][reg] + b;
            v = v > 0.f ? v : 0.01f * v;
            Vl[(lrbase + reg) * VLD + gn] = v * pe[reg];
        }
    }
    __syncthreads();

    // segment reduce: 2 (segment, col) pairs in flight across 256 threads
    const int colc = tid & 127;
    const int sg = tid >> 7;
    const int ns = nseg_s;
    for (int s2 = sg; s2 < ns; s2 += 2) {
        int a = segstart[s2];
        int bnd = (s2 + 1 < ns) ? segstart[s2 + 1] : 64;
        float sum = 0.f;
        for (int rr = a; rr < bnd; ++rr) sum += Vl[rr * VLD + colc];
        atomicAdd(&out[(size_t)segnode[s2] * 128 + colc], sum);
    }
}

extern "C" void kernel_launch(void* const* d_in, const int* in_sizes, int n_in,
                              void* d_out, int out_size, void* d_ws, size_t ws_size,
                              hipStream_t stream) {
    const float* nodes = (const float*)d_in[0];
    const float* edges = (const float*)d_in[1];
    const int*   eidx  = (const int*)d_in[2];     // row0 = sender, row1 = receiver
    const float* Wq = (const float*)d_in[3];
    const float* bq = (const float*)d_in[4];
    const float* Wk = (const float*)d_in[5];
    const float* bk = (const float*)d_in[6];
    const float* Wv = (const float*)d_in[7];
    const float* bv = (const float*)d_in[8];
    const int* sidx = eidx;
    const int* ridx = eidx + NE;

    // workspace layout (16B aligned):
    char* ws = (char*)d_ws;
    unsigned short* wq_bf = (unsigned short*)ws;          // 32768 (Wq) — Wq||Wk contiguous = stacked
    unsigned short* wv_bf = wq_bf + 65536;                // 16384
    unsigned short* q_bf  = (unsigned short*)(ws + 163840);
    unsigned short* k_bf  = q_bf + (size_t)NN * 128;
    char* ws2 = ws + 163840 + 2 * (size_t)NN * 128 * 2;   // after q,k (25.6 MB)
    float* p     = (float*)ws2;                           // NE floats (sorted order)
    float* denom = p + NE;                                // NN
    int*   cnt   = (int*)(denom + NN);                    // NN
    int*   offs  = cnt + NN;                              // NN
    int*   perm  = offs + NN;                             // NE
    int*   rs    = perm + NE;                             // NE   (total ~45 MB)
    float* out = (float*)d_out;

    hipMemsetAsync(out, 0, (size_t)NN * 128 * 4, stream);
    hipMemsetAsync(denom, 0, (size_t)NN * 4, stream);
    hipMemsetAsync(cnt, 0, (size_t)NN * 4, stream);

    cast_w_kernel<<<320, 256, 0, stream>>>(Wq, Wk, Wv, wq_bf);
    hist_kernel<<<(NE + 255) / 256, 256, 0, stream>>>(ridx, cnt);
    scan_kernel<<<1, 1024, 0, stream>>>(cnt, offs);
    scatter_kernel<<<(NE + 255) / 256, 256, 0, stream>>>(ridx, offs, perm, rs);
    proj_qk<<<(NN + 63) / 64, 256, 0, stream>>>(nodes, wq_bf, bq, bk, q_bf, k_bf, NN);
    logits_kernel<<<(NE + 255) / 256, 256, 0, stream>>>(q_bf, k_bf, sidx, perm, rs, p, denom);
    pnorm_kernel<<<(NE + 255) / 256, 256, 0, stream>>>(p, rs, denom);
    v_gemm_seg<<<NE / 64, 256, 0, stream>>>(edges, wv_bf, bv, p, perm, rs, out);
}

// Round 3
// 680.870 us; speedup vs baseline: 1.3050x; 1.2870x over previous
//
#include <hip/hip_runtime.h>
#include <hip/hip_bf16.h>
#include <cstdint>

#define NN 50000
#define NE 1600000
#define DV 256
#define DA 128

using floatx4 = __attribute__((ext_vector_type(4))) float;
using shortx8 = __attribute__((ext_vector_type(8))) short;

__device__ __forceinline__ unsigned short f2bf(float f) {
    union { float f; uint32_t u; } v; v.f = f;
    uint32_t u = v.u;
    uint32_t r = (u + 0x7FFFu + ((u >> 16) & 1u)) >> 16;   // RNE
    return (unsigned short)r;
}
__device__ __forceinline__ float bflo(uint32_t u) {
    union { uint32_t u; float f; } v; v.u = u << 16; return v.f;
}
__device__ __forceinline__ float bfhi(uint32_t u) {
    union { uint32_t u; float f; } v; v.u = u & 0xFFFF0000u; return v.f;
}

// ---------------- zero out + denom + cnt (replaces 3 memset nodes) --------
__global__ void init_zero(float4* __restrict__ out, float4* __restrict__ denom,
                          float4* __restrict__ cnt) {
    const float4 z = make_float4(0.f, 0.f, 0.f, 0.f);
    int i = blockIdx.x * blockDim.x + threadIdx.x;
    const int stride = gridDim.x * blockDim.x;
    for (int j = i; j < NN * 128 / 4; j += stride) out[j] = z;
    if (i < NN / 4) { denom[i] = z; cnt[i] = z; }
}

// ---------------- cast weights fp32 -> bf16 -------------------------------
__global__ void cast_w_kernel(const float* __restrict__ wq, const float* __restrict__ wk,
                              const float* __restrict__ wv, unsigned short* __restrict__ out) {
    int i = blockIdx.x * blockDim.x + threadIdx.x;
    if (i < 32768)       out[i] = f2bf(wq[i]);
    else if (i < 65536)  out[i] = f2bf(wk[i - 32768]);
    else if (i < 81920)  out[i] = f2bf(wv[i - 65536]);
}

// ---------------- sort-by-receiver infrastructure -------------------------
__global__ void hist_kernel(const int* __restrict__ ridx, int* __restrict__ cnt) {
    int e = blockIdx.x * blockDim.x + threadIdx.x;
    if (e < NE) atomicAdd(&cnt[ridx[e]], 1);
}

// single-block exclusive scan of cnt[NN] -> offs[NN]
__global__ __launch_bounds__(1024)
void scan_kernel(const int* __restrict__ cnt, int* __restrict__ offs) {
    __shared__ int part[1024];
    const int tid = threadIdx.x;
    const int PER = (NN + 1023) / 1024;   // 49
    int base = tid * PER;
    int s = 0;
    for (int i = 0; i < PER; ++i) { int idx = base + i; if (idx < NN) s += cnt[idx]; }
    part[tid] = s;
    __syncthreads();
    for (int off = 1; off < 1024; off <<= 1) {
        int v = (tid >= off) ? part[tid - off] : 0;
        __syncthreads();
        part[tid] += v;
        __syncthreads();
    }
    int excl = (tid == 0) ? 0 : part[tid - 1];
    for (int i = 0; i < PER; ++i) {
        int idx = base + i;
        if (idx < NN) { offs[idx] = excl; excl += cnt[idx]; }
    }
}

// scatter edges into receiver-sorted order; offs used as running cursor
__global__ void scatter_kernel(const int* __restrict__ ridx, int* __restrict__ offs,
                               int* __restrict__ perm, int* __restrict__ rs) {
    int e = blockIdx.x * blockDim.x + threadIdx.x;
    if (e >= NE) return;
    int r = ridx[e];
    int pos = atomicAdd(&offs[r], 1);
    perm[pos] = e;
    rs[pos] = r;
}

// ---------------- fused Q,K projection: [NN,256] x [256,256]^T ------------
__global__ __launch_bounds__(256)
void proj_qk(const float* __restrict__ A, const unsigned short* __restrict__ Wst,
             const float* __restrict__ bq, const float* __restrict__ bk,
             unsigned short* __restrict__ qbf, unsigned short* __restrict__ kbf, int M) {
    __shared__ unsigned short Al[64 * 32];
    __shared__ unsigned short Bl[256 * 32];
    const int tid = threadIdx.x;
    const int lane = tid & 63, w = tid >> 6;
    const int m0 = blockIdx.x * 64;
    constexpr int K = 256;

    floatx4 acc[16];
#pragma unroll
    for (int i = 0; i < 16; ++i) acc[i] = (floatx4)0.0f;

    for (int kk = 0; kk < K; kk += 32) {
#pragma unroll
        for (int it = 0; it < 2; ++it) {
            int j = tid + it * 256;
            int row = j >> 3;
            int c4 = (j & 7) * 4;
            float4 f = make_float4(0.f, 0.f, 0.f, 0.f);
            int gm = m0 + row;
            if (gm < M) f = *reinterpret_cast<const float4*>(A + (size_t)gm * K + kk + c4);
            ushort4 u; u.x = f2bf(f.x); u.y = f2bf(f.y); u.z = f2bf(f.z); u.w = f2bf(f.w);
            *reinterpret_cast<ushort4*>(&Al[row * 32 + c4]) = u;
        }
#pragma unroll
        for (int it = 0; it < 4; ++it) {
            int j = tid + it * 256;
            int row = j >> 2;
            int c8 = (j & 3) * 8;
            uint4 v = *reinterpret_cast<const uint4*>(Wst + (size_t)row * K + kk + c8);
            *reinterpret_cast<uint4*>(&Bl[row * 32 + c8]) = v;
        }
        __syncthreads();
        shortx8 af = *reinterpret_cast<const shortx8*>(&Al[(w * 16 + (lane & 15)) * 32 + 8 * (lane >> 4)]);
#pragma unroll
        for (int nt = 0; nt < 16; ++nt) {
            shortx8 bf = *reinterpret_cast<const shortx8*>(&Bl[(nt * 16 + (lane & 15)) * 32 + 8 * (lane >> 4)]);
            acc[nt] = __builtin_amdgcn_mfma_f32_16x16x32_bf16(af, bf, acc[nt], 0, 0, 0);
        }
        __syncthreads();
    }
    const int col = lane & 15;
    const int rbase = m0 + w * 16 + 4 * (lane >> 4);
#pragma unroll
    for (int nt = 0; nt < 16; ++nt) {
        int gn = nt * 16 + col;
        bool isq = gn < 128;
        int oc = isq ? gn : gn - 128;
        float b = isq ? bq[oc] : bk[oc];
        unsigned short* O = isq ? qbf : kbf;
#pragma unroll
        for (int reg = 0; reg < 4; ++reg) {
            int gm = rbase + reg;
            if (gm < M) {
                float v = acc[nt][reg] + b;
                v = v > 0.f ? v : 0.01f * v;
                O[(size_t)gm * 128 + oc] = f2bf(v);
            }
        }
    }
}

// ---- fused: per-edge logit+exp, V projection, in-block segment reduce ----
// out accumulates UNNORMALIZED numerator; denom accumulates exp-sums.
__global__ __launch_bounds__(256)
void v_gemm_fused(const float* __restrict__ Ed, const unsigned short* __restrict__ Wv,
                  const float* __restrict__ bv,
                  const unsigned short* __restrict__ qbf, const unsigned short* __restrict__ kbf,
                  const int* __restrict__ sidx,
                  const int* __restrict__ perm, const int* __restrict__ rs,
                  float* __restrict__ out, float* __restrict__ denom) {
    constexpr int K = 128;
    constexpr int VLD = 129;                    // padded row stride (floats)
    __shared__ float Vl[64 * VLD];              // 33 KB; MFMA staging aliased inside
    __shared__ float pl[64];
    __shared__ int segstart[64];
    __shared__ int segnode[64];
    __shared__ int nseg_s;
    unsigned short* Al = reinterpret_cast<unsigned short*>(Vl);          // 4 KB
    unsigned short* Bl = reinterpret_cast<unsigned short*>(Vl) + 2048;   // 8 KB

    const int tid = threadIdx.x;
    const int lane = tid & 63, w = tid >> 6;
    const int m0 = blockIdx.x * 64;             // NE % 64 == 0

    // segment boundaries within this block's 64 sorted edges (wave 0)
    if (w == 0) {
        int r = rs[m0 + lane];
        int prev = (lane == 0) ? -1 : rs[m0 + lane - 1];
        bool flag = (lane == 0) || (r != prev);
        unsigned long long mask = __ballot(flag);
        int ns = __popcll(mask);
        int pos = __popcll(mask & ((1ull << lane) - 1ull));
        if (flag) { segstart[pos] = lane; segnode[pos] = r; }
        if (lane == 0) nseg_s = ns;
    }

    // ---- phase 1: per-edge logit -> p (4 lanes per edge, 32 dims each) ----
    {
        const int eL = tid >> 2;                // 0..63
        const int qt = tid & 3;                 // 32-dim quarter
        int posE = m0 + eL;
        int e = perm[posE];
        int s = sidx[e];
        int r = rs[posE];
        const uint4* kp = reinterpret_cast<const uint4*>(kbf + (size_t)s * 128 + qt * 32);
        const uint4* qp = reinterpret_cast<const uint4*>(qbf + (size_t)r * 128 + qt * 32);
        float acc = 0.f;
#pragma unroll
        for (int i = 0; i < 4; ++i) {
            uint4 qa = qp[i], ka = kp[i];
            acc += bflo(qa.x) * bflo(ka.x) + bfhi(qa.x) * bfhi(ka.x);
            acc += bflo(qa.y) * bflo(ka.y) + bfhi(qa.y) * bfhi(ka.y);
            acc += bflo(qa.z) * bflo(ka.z) + bfhi(qa.z) * bfhi(ka.z);
            acc += bflo(qa.w) * bflo(ka.w) + bfhi(qa.w) * bfhi(ka.w);
        }
        acc += __shfl_xor(acc, 1);
        acc += __shfl_xor(acc, 2);
        if (qt == 0) pl[eL] = __expf(acc * 0.08838834764831845f);
    }

    // gathered edge ids for A staging (2 rows per thread)
    const int row0 = tid >> 3;                  // 0..31
    const int e0 = perm[m0 + row0];
    const int e1 = perm[m0 + row0 + 32];
    const int c4 = (tid & 7) * 4;

    floatx4 acc[8];
#pragma unroll
    for (int i = 0; i < 8; ++i) acc[i] = (floatx4)0.0f;

    for (int kk = 0; kk < K; kk += 32) {
        {
            float4 f0 = *reinterpret_cast<const float4*>(Ed + (size_t)e0 * K + kk + c4);
            float4 f1 = *reinterpret_cast<const float4*>(Ed + (size_t)e1 * K + kk + c4);
            ushort4 u0; u0.x = f2bf(f0.x); u0.y = f2bf(f0.y); u0.z = f2bf(f0.z); u0.w = f2bf(f0.w);
            ushort4 u1; u1.x = f2bf(f1.x); u1.y = f2bf(f1.y); u1.z = f2bf(f1.z); u1.w = f2bf(f1.w);
            *reinterpret_cast<ushort4*>(&Al[row0 * 32 + c4]) = u0;
            *reinterpret_cast<ushort4*>(&Al[(row0 + 32) * 32 + c4]) = u1;
        }
#pragma unroll
        for (int it = 0; it < 2; ++it) {
            int j = tid + it * 256;
            int row = j >> 2;
            int c8 = (j & 3) * 8;
            uint4 v = *reinterpret_cast<const uint4*>(Wv + (size_t)row * K + kk + c8);
            *reinterpret_cast<uint4*>(&Bl[row * 32 + c8]) = v;
        }
        __syncthreads();
        shortx8 af = *reinterpret_cast<const shortx8*>(&Al[(w * 16 + (lane & 15)) * 32 + 8 * (lane >> 4)]);
#pragma unroll
        for (int nt = 0; nt < 8; ++nt) {
            shortx8 bf = *reinterpret_cast<const shortx8*>(&Bl[(nt * 16 + (lane & 15)) * 32 + 8 * (lane >> 4)]);
            acc[nt] = __builtin_amdgcn_mfma_f32_16x16x32_bf16(af, bf, acc[nt], 0, 0, 0);
        }
        __syncthreads();
    }

    // epilogue: bias + lrelu, scale by p, stash rows in LDS
    const int col = lane & 15;
    const int lrbase = w * 16 + 4 * (lane >> 4);
    float pe[4];
#pragma unroll
    for (int reg = 0; reg < 4; ++reg) pe[reg] = pl[lrbase + reg];
#pragma unroll
    for (int nt = 0; nt < 8; ++nt) {
        int gn = nt * 16 + col;
        float b = bv[gn];
#pragma unroll
        for (int reg = 0; reg < 4; ++reg) {
            float v = acc[nt][reg] + b;
            v = v > 0.f ? v : 0.01f * v;
            Vl[(lrbase + reg) * VLD + gn] = v * pe[reg];
        }
    }
    __syncthreads();

    // segment reduce: numerator cols + p-sums; ~nseg atomics per block
    const int colc = tid & 127;
    const int sg = tid >> 7;
    const int ns = nseg_s;
    for (int s2 = sg; s2 < ns; s2 += 2) {
        int a = segstart[s2];
        int bnd = (s2 + 1 < ns) ? segstart[s2 + 1] : 64;
        float sum = 0.f;
        for (int rr = a; rr < bnd; ++rr) sum += Vl[rr * VLD + colc];
        atomicAdd(&out[(size_t)segnode[s2] * 128 + colc], sum);
        if (colc == 0) {
            float ds = 0.f;
            for (int rr = a; rr < bnd; ++rr) ds += pl[rr];
            atomicAdd(&denom[segnode[s2]], ds);
        }
    }
}

// ---------------- normalize: out /= denom[node] ---------------------------
__global__ void normalize_kernel(float* __restrict__ out, const float* __restrict__ denom) {
    int i = blockIdx.x * blockDim.x + threadIdx.x;   // one float4 each
    if (i >= NN * 128 / 4) return;
    int node = (i * 4) >> 7;
    float d = denom[node];
    float inv = d > 0.f ? 1.0f / d : 0.f;
    float4* o = reinterpret_cast<float4*>(out) + i;
    float4 v = *o;
    v.x *= inv; v.y *= inv; v.z *= inv; v.w *= inv;
    *o = v;
}

extern "C" void kernel_launch(void* const* d_in, const int* in_sizes, int n_in,
                              void* d_out, int out_size, void* d_ws, size_t ws_size,
                              hipStream_t stream) {
    const float* nodes = (const float*)d_in[0];
    const float* edges = (const float*)d_in[1];
    const int*   eidx  = (const int*)d_in[2];     // row0 = sender, row1 = receiver
    const float* Wq = (const float*)d_in[3];
    const float* bq = (const float*)d_in[4];
    const float* Wk = (const float*)d_in[5];
    const float* bk = (const float*)d_in[6];
    const float* Wv = (const float*)d_in[7];
    const float* bv = (const float*)d_in[8];
    const int* sidx = eidx;
    const int* ridx = eidx + NE;

    // workspace layout (16B aligned):
    char* ws = (char*)d_ws;
    unsigned short* wq_bf = (unsigned short*)ws;          // Wq||Wk contiguous (stacked), then Wv
    unsigned short* wv_bf = wq_bf + 65536;
    unsigned short* q_bf  = (unsigned short*)(ws + 163840);
    unsigned short* k_bf  = q_bf + (size_t)NN * 128;
    char* ws2 = ws + 163840 + 2 * (size_t)NN * 128 * 2;   // after q,k (25.6 MB)
    float* denom = (float*)ws2;                           // NN
    int*   cnt   = (int*)(denom + NN);                    // NN
    int*   offs  = cnt + NN;                              // NN
    int*   perm  = offs + NN;                             // NE
    int*   rs    = perm + NE;                             // NE
    float* out = (float*)d_out;

    init_zero<<<2048, 256, 0, stream>>>((float4*)out, (float4*)denom, (float4*)cnt);
    cast_w_kernel<<<320, 256, 0, stream>>>(Wq, Wk, Wv, wq_bf);
    hist_kernel<<<(NE + 255) / 256, 256, 0, stream>>>(ridx, cnt);
    scan_kernel<<<1, 1024, 0, stream>>>(cnt, offs);
    scatter_kernel<<<(NE + 255) / 256, 256, 0, stream>>>(ridx, offs, perm, rs);
    proj_qk<<<(NN + 63) / 64, 256, 0, stream>>>(nodes, wq_bf, bq, bk, q_bf, k_bf, NN);
    v_gemm_fused<<<NE / 64, 256, 0, stream>>>(edges, wv_bf, bv, q_bf, k_bf, sidx, perm, rs, out, denom);
    normalize_kernel<<<(NN * 128 / 4 + 255) / 256, 256, 0, stream>>>(out, denom);
}

// Round 4
// 640.192 us; speedup vs baseline: 1.3879x; 1.0635x over previous
//
#include <hip/hip_runtime.h>
#include <hip/hip_bf16.h>
#include <cstdint>

#define NN 50000
#define NE 1600000
#define DV 256
#define DA 128

using floatx4 = __attribute__((ext_vector_type(4))) float;
using shortx8 = __attribute__((ext_vector_type(8))) short;

__device__ __forceinline__ unsigned short f2bf(float f) {
    union { float f; uint32_t u; } v; v.f = f;
    uint32_t u = v.u;
    uint32_t r = (u + 0x7FFFu + ((u >> 16) & 1u)) >> 16;   // RNE
    return (unsigned short)r;
}
__device__ __forceinline__ float bflo(uint32_t u) {
    union { uint32_t u; float f; } v; v.u = u << 16; return v.f;
}
__device__ __forceinline__ float bfhi(uint32_t u) {
    union { uint32_t u; float f; } v; v.u = u & 0xFFFF0000u; return v.f;
}
__device__ __forceinline__ shortx8 pack8(float4 a, float4 b) {
    shortx8 u;
    u[0] = (short)f2bf(a.x); u[1] = (short)f2bf(a.y);
    u[2] = (short)f2bf(a.z); u[3] = (short)f2bf(a.w);
    u[4] = (short)f2bf(b.x); u[5] = (short)f2bf(b.y);
    u[6] = (short)f2bf(b.z); u[7] = (short)f2bf(b.w);
    return u;
}

// ---------------- zero out + denom + cnt ----------------------------------
__global__ void init_zero(float4* __restrict__ out, float4* __restrict__ denom,
                          float4* __restrict__ cnt) {
    const float4 z = make_float4(0.f, 0.f, 0.f, 0.f);
    int i = blockIdx.x * blockDim.x + threadIdx.x;
    const int stride = gridDim.x * blockDim.x;
    for (int j = i; j < NN * 128 / 4; j += stride) out[j] = z;
    if (i < NN / 4) { denom[i] = z; cnt[i] = z; }
}

// ---------------- cast weights fp32 -> bf16 -------------------------------
__global__ void cast_w_kernel(const float* __restrict__ wq, const float* __restrict__ wk,
                              const float* __restrict__ wv, unsigned short* __restrict__ out) {
    int i = blockIdx.x * blockDim.x + threadIdx.x;
    if (i < 32768)       out[i] = f2bf(wq[i]);
    else if (i < 65536)  out[i] = f2bf(wk[i - 32768]);
    else if (i < 81920)  out[i] = f2bf(wv[i - 65536]);
}

// ---------------- sort-by-receiver infrastructure -------------------------
__global__ void hist_kernel(const int* __restrict__ ridx, int* __restrict__ cnt) {
    int e = blockIdx.x * blockDim.x + threadIdx.x;
    if (e < NE) atomicAdd(&cnt[ridx[e]], 1);
}

__global__ __launch_bounds__(1024)
void scan_kernel(const int* __restrict__ cnt, int* __restrict__ offs) {
    __shared__ int part[1024];
    const int tid = threadIdx.x;
    const int PER = (NN + 1023) / 1024;   // 49
    int base = tid * PER;
    int s = 0;
    for (int i = 0; i < PER; ++i) { int idx = base + i; if (idx < NN) s += cnt[idx]; }
    part[tid] = s;
    __syncthreads();
    for (int off = 1; off < 1024; off <<= 1) {
        int v = (tid >= off) ? part[tid - off] : 0;
        __syncthreads();
        part[tid] += v;
        __syncthreads();
    }
    int excl = (tid == 0) ? 0 : part[tid - 1];
    for (int i = 0; i < PER; ++i) {
        int idx = base + i;
        if (idx < NN) { offs[idx] = excl; excl += cnt[idx]; }
    }
}

__global__ void scatter_kernel(const int* __restrict__ ridx, int* __restrict__ offs,
                               int* __restrict__ perm) {
    int e = blockIdx.x * blockDim.x + threadIdx.x;
    if (e >= NE) return;
    int r = ridx[e];
    int pos = atomicAdd(&offs[r], 1);
    perm[pos] = e;
}

// ---------------- fused Q,K projection: [NN,256] x [256,256]^T ------------
__global__ __launch_bounds__(256)
void proj_qk(const float* __restrict__ A, const unsigned short* __restrict__ Wst,
             const float* __restrict__ bq, const float* __restrict__ bk,
             unsigned short* __restrict__ qbf, unsigned short* __restrict__ kbf, int M) {
    __shared__ unsigned short Al[64 * 32];
    __shared__ unsigned short Bl[256 * 32];
    const int tid = threadIdx.x;
    const int lane = tid & 63, w = tid >> 6;
    const int m0 = blockIdx.x * 64;
    constexpr int K = 256;

    floatx4 acc[16];
#pragma unroll
    for (int i = 0; i < 16; ++i) acc[i] = (floatx4)0.0f;

    for (int kk = 0; kk < K; kk += 32) {
#pragma unroll
        for (int it = 0; it < 2; ++it) {
            int j = tid + it * 256;
            int row = j >> 3;
            int c4 = (j & 7) * 4;
            float4 f = make_float4(0.f, 0.f, 0.f, 0.f);
            int gm = m0 + row;
            if (gm < M) f = *reinterpret_cast<const float4*>(A + (size_t)gm * K + kk + c4);
            ushort4 u; u.x = f2bf(f.x); u.y = f2bf(f.y); u.z = f2bf(f.z); u.w = f2bf(f.w);
            *reinterpret_cast<ushort4*>(&Al[row * 32 + c4]) = u;
        }
#pragma unroll
        for (int it = 0; it < 4; ++it) {
            int j = tid + it * 256;
            int row = j >> 2;
            int c8 = (j & 3) * 8;
            uint4 v = *reinterpret_cast<const uint4*>(Wst + (size_t)row * K + kk + c8);
            *reinterpret_cast<uint4*>(&Bl[row * 32 + c8]) = v;
        }
        __syncthreads();
        shortx8 af = *reinterpret_cast<const shortx8*>(&Al[(w * 16 + (lane & 15)) * 32 + 8 * (lane >> 4)]);
#pragma unroll
        for (int nt = 0; nt < 16; ++nt) {
            shortx8 bf = *reinterpret_cast<const shortx8*>(&Bl[(nt * 16 + (lane & 15)) * 32 + 8 * (lane >> 4)]);
            acc[nt] = __builtin_amdgcn_mfma_f32_16x16x32_bf16(af, bf, acc[nt], 0, 0, 0);
        }
        __syncthreads();
    }
    const int col = lane & 15;
    const int rbase = m0 + w * 16 + 4 * (lane >> 4);
#pragma unroll
    for (int nt = 0; nt < 16; ++nt) {
        int gn = nt * 16 + col;
        bool isq = gn < 128;
        int oc = isq ? gn : gn - 128;
        float b = isq ? bq[oc] : bk[oc];
        unsigned short* O = isq ? qbf : kbf;
#pragma unroll
        for (int reg = 0; reg < 4; ++reg) {
            int gm = rbase + reg;
            if (gm < M) {
                float v = acc[nt][reg] + b;
                v = v > 0.f ? v : 0.01f * v;
                O[(size_t)gm * 128 + oc] = f2bf(v);
            }
        }
    }
}

// ---- fused: logits+exp, V projection (2-phase pipelined), segment reduce --
// BM=128 edges/block, 512 threads (8 waves), one barrier per K-iter.
// LDS map (bytes):
//   [0,32768)      Bf: Wv fragment-linear  |  aliased post-loop: Vl bf16 [128][128]
//   [32768,40960)  A buf0 (128x32 bf16, XOR chunk swizzle)
//   [40960,49152)  A buf1
//   [49152,49664)  rs_local[128] int
//   [49664,50176)  pl[128] float
//   [50176,50688)  segstart[128] int
//   [50688,51200)  segnode[128] int
//   [51200,51216)  masks[2] u64
//   [51216,51220)  nseg int
__global__ __launch_bounds__(512)
void v_gemm_fused(const float* __restrict__ Ed, const unsigned short* __restrict__ wv_bf,
                  const float* __restrict__ bv,
                  const unsigned short* __restrict__ qbf, const unsigned short* __restrict__ kbf,
                  const int* __restrict__ sidx, const int* __restrict__ ridx,
                  const int* __restrict__ perm,
                  float* __restrict__ out, float* __restrict__ denom) {
    __shared__ __align__(16) char smem[51264];
    unsigned short* Bf = reinterpret_cast<unsigned short*>(smem);
    unsigned short* Vl = reinterpret_cast<unsigned short*>(smem);        // alias, post-loop
    int*   rs_local = reinterpret_cast<int*>(smem + 49152);
    float* pl       = reinterpret_cast<float*>(smem + 49664);
    int*   segstart = reinterpret_cast<int*>(smem + 50176);
    int*   segnode  = reinterpret_cast<int*>(smem + 50688);
    unsigned long long* masks = reinterpret_cast<unsigned long long*>(smem + 51200);
    int* nseg_s = reinterpret_cast<int*>(smem + 51216);

    const int tid = threadIdx.x;
    const int lane = tid & 63, w = tid >> 6;
    const size_t m0 = (size_t)blockIdx.x * 128;    // NE % 128 == 0

    // ---- prologue: everything issued before one barrier ----
    const int erow = tid >> 2;                     // 0..127 (edge within block)
    const int qt = tid & 3;                        // 32-dim quarter for logits
    const int e_id = perm[m0 + erow];
    const int sN = sidx[e_id];
    const int rN = ridx[e_id];
    if (qt == 0) rs_local[erow] = rN;

    // phase 1: logit -> p  (4 lanes per edge)
    {
        const uint4* kp = reinterpret_cast<const uint4*>(kbf + (size_t)sN * 128 + qt * 32);
        const uint4* qp = reinterpret_cast<const uint4*>(qbf + (size_t)rN * 128 + qt * 32);
        float acq = 0.f;
#pragma unroll
        for (int i = 0; i < 4; ++i) {
            uint4 qa = qp[i], ka = kp[i];
            acq += bflo(qa.x) * bflo(ka.x) + bfhi(qa.x) * bfhi(ka.x);
            acq += bflo(qa.y) * bflo(ka.y) + bfhi(qa.y) * bfhi(ka.y);
            acq += bflo(qa.z) * bflo(ka.z) + bfhi(qa.z) * bfhi(ka.z);
            acq += bflo(qa.w) * bflo(ka.w) + bfhi(qa.w) * bfhi(ka.w);
        }
        acq += __shfl_xor(acq, 1);
        acq += __shfl_xor(acq, 2);
        if (qt == 0) pl[erow] = __expf(acq * 0.08838834764831845f);
    }

    // Wv -> Bf fragment-linear: frag (kt,nt), lane l holds B[k=kt*32+8*(l>>4)..+8][n=nt*16+(l&15)]
#pragma unroll
    for (int it = 0; it < 4; ++it) {
        int s = tid + it * 512;
        int g = s >> 6, l = s & 63;
        int kt4 = g >> 3, nt = g & 7;
        uint4 v = *reinterpret_cast<const uint4*>(
            wv_bf + (size_t)(nt * 16 + (l & 15)) * 128 + kt4 * 32 + 8 * (l >> 4));
        *reinterpret_cast<uint4*>(smem + s * 16) = v;
    }

    // A tile kt=0 -> buf0 (XOR chunk swizzle: chunk' = chunk ^ ((row>>1)&3))
    const float* arow = Ed + (size_t)e_id * 128;
    const int cst = (tid & 3) * 8;                     // k-offset (floats) within 32-chunk
    const int chunkp = (tid & 3) ^ ((tid >> 3) & 3);   // (t&3) ^ ((row>>1)&3)
    {
        float4 fa = *reinterpret_cast<const float4*>(arow + cst);
        float4 fb = *reinterpret_cast<const float4*>(arow + cst + 4);
        shortx8 u = pack8(fa, fb);
        *reinterpret_cast<shortx8*>(smem + 32768 + erow * 64 + chunkp * 16) = u;
    }
    __syncthreads();

    // segment masks (waves 0,1 cover positions 0..127)
    if (tid < 128) {
        bool flag = (tid == 0) || (rs_local[tid] != rs_local[tid - 1]);
        unsigned long long mk = __ballot(flag);
        if (lane == 0) masks[w] = mk;
    }
    __syncthreads();
    if (tid < 128) {
        bool flag = (tid == 0) || (rs_local[tid] != rs_local[tid - 1]);
        unsigned long long mk0 = masks[0], mk1 = masks[1];
        if (tid == 0) *nseg_s = __popcll(mk0) + __popcll(mk1);
        if (flag) {
            int rank = (tid < 64)
                ? __popcll(mk0 & ((1ull << tid) - 1ull))
                : __popcll(mk0) + ((tid == 64) ? 0 : __popcll(mk1 & ((1ull << (tid - 64)) - 1ull)));
            segstart[rank] = tid;
            segnode[rank] = rs_local[tid];
        }
    }
    // (visibility of segstart/segnode to the reduce phase is guaranteed by the
    //  K-loop + epilogue barriers below)

    // ---- K loop: 4 iters, one barrier each, prefetch overlapped ----
    floatx4 acc[8];
#pragma unroll
    for (int i = 0; i < 8; ++i) acc[i] = (floatx4)0.0f;
    const int afr_off = (w * 16 + (lane & 15)) * 64 +
                        (((lane >> 4) ^ (((lane & 15) >> 1) & 3)) << 4);
#pragma unroll
    for (int kt = 0; kt < 4; ++kt) {
        const int rbase = (kt & 1) ? 40960 : 32768;
        const int wbase = (kt & 1) ? 32768 : 40960;
        float4 fa, fb;
        if (kt < 3) {   // issue next-tile loads EARLY (overlap with MFMA)
            fa = *reinterpret_cast<const float4*>(arow + (kt + 1) * 32 + cst);
            fb = *reinterpret_cast<const float4*>(arow + (kt + 1) * 32 + cst + 4);
        }
        shortx8 af = *reinterpret_cast<const shortx8*>(smem + rbase + afr_off);
#pragma unroll
        for (int nt = 0; nt < 8; ++nt) {
            shortx8 bfr = *reinterpret_cast<const shortx8*>(smem + (((kt * 8 + nt) * 64 + lane) << 4));
            acc[nt] = __builtin_amdgcn_mfma_f32_16x16x32_bf16(af, bfr, acc[nt], 0, 0, 0);
        }
        if (kt < 3) {
            shortx8 u = pack8(fa, fb);
            *reinterpret_cast<shortx8*>(smem + wbase + erow * 64 + chunkp * 16) = u;
        }
        __syncthreads();
    }

    // ---- epilogue: bias+lrelu, scale by p, stash bf16 rows (alias Bf) ----
    const int colb = lane & 15;
    const int rquad = w * 16 + 4 * (lane >> 4);
    float pe[4];
#pragma unroll
    for (int reg = 0; reg < 4; ++reg) pe[reg] = pl[rquad + reg];
#pragma unroll
    for (int nt = 0; nt < 8; ++nt) {
        float b = bv[nt * 16 + colb];
#pragma unroll
        for (int reg = 0; reg < 4; ++reg) {
            float v = acc[nt][reg] + b;
            v = v > 0.f ? v : 0.01f * v;
            Vl[(rquad + reg) * 128 + nt * 16 + colb] = f2bf(v * pe[reg]);
        }
    }
    __syncthreads();

    // ---- segment reduce: interior segments = plain store, boundary = atomic
    const int colc = tid & 127;
    const int sg = tid >> 7;                 // 4 segment streams
    const int ns = *nseg_s;
    for (int s2 = sg; s2 < ns; s2 += 4) {
        int a = segstart[s2];
        int bnd = (s2 + 1 < ns) ? segstart[s2 + 1] : 128;
        float sum = 0.f;
        for (int rr = a; rr < bnd; ++rr) sum += bflo((uint32_t)Vl[rr * 128 + colc]);
        int node = segnode[s2];
        bool interior = (s2 > 0) && (s2 + 1 < ns);
        if (interior) out[(size_t)node * 128 + colc] = sum;
        else          atomicAdd(&out[(size_t)node * 128 + colc], sum);
        if (colc == 0) {
            float ds = 0.f;
            for (int rr = a; rr < bnd; ++rr) ds += pl[rr];
            if (interior) denom[node] = ds;
            else          atomicAdd(&denom[node], ds);
        }
    }
}

// ---------------- normalize: out /= denom[node] ---------------------------
__global__ void normalize_kernel(float* __restrict__ out, const float* __restrict__ denom) {
    int i = blockIdx.x * blockDim.x + threadIdx.x;   // one float4 each
    if (i >= NN * 128 / 4) return;
    int node = (i * 4) >> 7;
    float d = denom[node];
    float inv = d > 0.f ? 1.0f / d : 0.f;
    float4* o = reinterpret_cast<float4*>(out) + i;
    float4 v = *o;
    v.x *= inv; v.y *= inv; v.z *= inv; v.w *= inv;
    *o = v;
}

extern "C" void kernel_launch(void* const* d_in, const int* in_sizes, int n_in,
                              void* d_out, int out_size, void* d_ws, size_t ws_size,
                              hipStream_t stream) {
    const float* nodes = (const float*)d_in[0];
    const float* edges = (const float*)d_in[1];
    const int*   eidx  = (const int*)d_in[2];     // row0 = sender, row1 = receiver
    const float* Wq = (const float*)d_in[3];
    const float* bq = (const float*)d_in[4];
    const float* Wk = (const float*)d_in[5];
    const float* bk = (const float*)d_in[6];
    const float* Wv = (const float*)d_in[7];
    const float* bv = (const float*)d_in[8];
    const int* sidx = eidx;
    const int* ridx = eidx + NE;

    // workspace layout (16B aligned):
    char* ws = (char*)d_ws;
    unsigned short* wq_bf = (unsigned short*)ws;          // Wq||Wk stacked, then Wv
    unsigned short* wv_bf = wq_bf + 65536;
    unsigned short* q_bf  = (unsigned short*)(ws + 163840);
    unsigned short* k_bf  = q_bf + (size_t)NN * 128;
    char* ws2 = ws + 163840 + 2 * (size_t)NN * 128 * 2;   // after q,k (25.6 MB)
    float* denom = (float*)ws2;                           // NN
    int*   cnt   = (int*)(denom + NN);                    // NN
    int*   offs  = cnt + NN;                              // NN
    int*   perm  = offs + NN;                             // NE
    float* out = (float*)d_out;

    init_zero<<<2048, 256, 0, stream>>>((float4*)out, (float4*)denom, (float4*)cnt);
    cast_w_kernel<<<320, 256, 0, stream>>>(Wq, Wk, Wv, wq_bf);
    hist_kernel<<<(NE + 255) / 256, 256, 0, stream>>>(ridx, cnt);
    scan_kernel<<<1, 1024, 0, stream>>>(cnt, offs);
    scatter_kernel<<<(NE + 255) / 256, 256, 0, stream>>>(ridx, offs, perm);
    proj_qk<<<(NN + 63) / 64, 256, 0, stream>>>(nodes, wq_bf, bq, bk, q_bf, k_bf, NN);
    v_gemm_fused<<<NE / 128, 512, 0, stream>>>(edges, wv_bf, bv, q_bf, k_bf, sidx, ridx,
                                               perm, out, denom);
    normalize_kernel<<<(NN * 128 / 4 + 255) / 256, 256, 0, stream>>>(out, denom);
}